// Round 16
// baseline (3801.904 us; speedup 1.0000x reference)
//
#include <hip/hip_runtime.h>
#include <math.h>

// Sizes fixed by the problem.
#define B_TOT 131072
#define M_N   1024
#define BS    128      // Cholesky block size
#define NBK   8        // M_N / BS

typedef float    f32x4 __attribute__((ext_vector_type(4)));
typedef _Float16 f16x8 __attribute__((ext_vector_type(8)));

// Workspace layout (bytes). Total ~17 MB.
enum : size_t {
    OFF_KF  = 0,                          // fp32 K (Schur-updated)  4 MB
    OFF_LF  = (size_t)4 << 20,            // fp32 L off-diag strips  4 MB
    OFF_WF  = (size_t)8 << 20,            // fp32 W = L^-1 (lower)   4 MB
    OFF_WPH = (size_t)12 << 20,           // fp16 W packed hi        2 MB
    OFF_WPL = (size_t)14 << 20,           // fp16 W packed lo        2 MB
    OFF_PF  = (size_t)16 << 20,           // fp32 params (6)
    OFF_ZT  = ((size_t)16 << 20) + 256,   // fp32 Zs_t [5][1024]     20 KB
};

__device__ __constant__ float c_zscale[5] = {0.15f, 0.1f, 0.05f, 800.0f, 20.0f};
__device__ __constant__ float c_zshift[5] = {0.0f, 0.0f, 0.0f, 600.0f, 5.0f};

// ---------------- fused: params + Zst + K = matern52 + jitter (fp32) ----------------
__global__ __launch_bounds__(256) void k_build(const float* __restrict__ log_ls,
                                               const float* __restrict__ log_var,
                                               const float* __restrict__ Zraw,
                                               float* __restrict__ Kf,
                                               float* __restrict__ pf,
                                               float* __restrict__ Zst) {
    __shared__ float ps[6];
    __shared__ float zsi[5];
    int tid = threadIdx.x;
    if (tid < 5) ps[tid] = 1.0f / (__expf(log_ls[tid]) + 1e-8f);
    if (tid == 5) ps[5] = __expf(log_var[0]);
    __syncthreads();
    int i = blockIdx.x >> 2;
    int j = (blockIdx.x & 3) * 256 + tid;
    if (tid < 5) zsi[tid] = (Zraw[i * 5 + tid] * c_zscale[tid] + c_zshift[tid]) * ps[tid];
    __syncthreads();
    float d2 = 0.0f;
#pragma unroll
    for (int d = 0; d < 5; ++d) {
        float zj = (Zraw[j * 5 + d] * c_zscale[d] + c_zshift[d]) * ps[d];
        float df = zsi[d] - zj;
        d2 += df * df;
    }
    float dd = d2 + 1e-8f;
    float dist = sqrtf(dd);
    float s = 2.23606798f * dist;
    float v = ps[5] * (1.0f + s + 1.66666667f * dd) * __expf(-s);
    if (i == j) v += 1e-4f;
    Kf[(size_t)i * M_N + j] = v;
    if (blockIdx.x < 4) {
        int m = blockIdx.x * 256 + tid;
#pragma unroll
        for (int d = 0; d < 5; ++d)
            Zst[d * M_N + m] = (Zraw[m * 5 + d] * c_zscale[d] + c_zshift[d]) * ps[d];
    }
    if (blockIdx.x == 4 && tid < 6) pf[tid] = ps[tid];
}

// ---------------- standalone Cholesky diag block kb=0 (r12-verified) ----------------
__global__ __launch_bounds__(512) void kw_diag(float* __restrict__ Kf,
                                               float* __restrict__ Wf, int kb) {
    if (blockIdx.x) return;   // grid padding (tiny-grid stall mitigation)
    __shared__ float As[128][129];
    __shared__ float sinv[128];
    int tid = threadIdx.x;
    int r0 = kb * BS;
    for (int idx = tid; idx < BS * BS; idx += 512) {
        int rr = idx >> 7, cc = idx & 127;
        As[rr][cc] = Kf[(size_t)(r0 + rr) * M_N + r0 + cc];
    }
    __syncthreads();

    int r = tid & 127, q = tid >> 7;
    for (int p = 0; p < 16; ++p) {
        int j0 = p * 8;
        for (int j = j0; j < j0 + 8; ++j) {
            if (tid == j) {
                float d = sqrtf(As[j][j]);
                As[j][j] = d;
                sinv[j] = 1.0f / d;
            }
            __syncthreads();
            float arj = 0.0f;
            if (q == 0 && r > j) {
                arj = As[r][j] * sinv[j];
                As[r][j] = arj;
            }
            __syncthreads();
            if (q == 0 && r > j) {
#pragma unroll
                for (int c = j + 1; c < j0 + 8; ++c)
                    As[r][c] -= arj * As[c][j];
            }
        }
        __syncthreads();
        if (p < 15) {
            float a[8];
#pragma unroll
            for (int t = 0; t < 8; ++t) a[t] = As[r][j0 + t];
            for (int c = j0 + 8 + q; c < 128; c += 4) {
                if (r >= c) {
                    float s = As[r][c];
#pragma unroll
                    for (int t = 0; t < 8; ++t) s -= a[t] * As[c][j0 + t];
                    As[r][c] = s;
                }
            }
        }
        __syncthreads();
    }

    if (tid < 128) {
        int c = tid;
        for (int rb = 0; rb < 16; ++rb) {
            int r0b = rb * 8;
            if (c >= r0b + 8) continue;
            float s[8];
#pragma unroll
            for (int i = 0; i < 8; ++i) s[i] = 0.0f;
            for (int t = 0; t < r0b; ++t) {
                if (t >= c) {
                    float xt = (t == c) ? sinv[c] : As[c][t];
#pragma unroll
                    for (int i = 0; i < 8; ++i) s[i] += As[r0b + i][t] * xt;
                }
            }
            float xloc[8];
#pragma unroll
            for (int i = 0; i < 8; ++i) {
                int rr = r0b + i;
                float v = 0.0f;
                if (rr >= c) {
                    v = ((rr == c) ? 1.0f : 0.0f) - s[i];
#pragma unroll
                    for (int t2 = 0; t2 < i; ++t2) {
                        int tt = r0b + t2;
                        if (tt >= c) v -= As[rr][tt] * xloc[t2];
                    }
                    v *= sinv[rr];
                    if (rr > c) As[c][rr] = v;
                }
                xloc[i] = v;
            }
        }
    }
    __syncthreads();
    for (int idx = tid; idx < BS * BS; idx += 512) {
        int rr = idx >> 7, cc = idx & 127;
        if (rr >= cc)
            Wf[(size_t)(r0 + rr) * M_N + r0 + cc] = (rr == cc) ? sinv[rr] : As[cc][rr];
    }
}

// ---------------- strip: S(64x128) = A21[row0..] * W11^T (fp32, into LDS) -------------
static __device__ void d_strip(const float* __restrict__ Kf, const float* __restrict__ Wf,
                               int cb, int row0, float (*S)[129],
                               float (*Ast)[17], float (*Wst)[128], int tid) {
    int c = tid & 127, q = tid >> 7;
    float acc[32];
#pragma unroll
    for (int i = 0; i < 32; ++i) acc[i] = 0.0f;
    for (int tc = 0; tc < 8; ++tc) {
        int tb = tc * 16;
        __syncthreads();
        for (int idx = tid; idx < 64 * 16; idx += 256) {
            int rr = idx >> 4, tt = idx & 15;
            Ast[rr][tt] = Kf[(size_t)(row0 + rr) * M_N + cb + tb + tt];
        }
        for (int idx = tid; idx < 128 * 16; idx += 256) {
            int cc = idx >> 4, tt = idx & 15;
            Wst[tt][cc] = (tb + tt <= cc) ? Wf[(size_t)(cb + cc) * M_N + cb + tb + tt] : 0.0f;
        }
        __syncthreads();
#pragma unroll
        for (int t = 0; t < 16; ++t) {
            float w = Wst[t][c];
#pragma unroll
            for (int i = 0; i < 32; ++i) acc[i] += Ast[q * 32 + i][t] * w;
        }
    }
    __syncthreads();
#pragma unroll
    for (int i = 0; i < 32; ++i) S[q * 32 + i][c] = acc[i];
}

// ---------------- diag factor + inverse, 256 threads (r12-verified) ----------------
static __device__ void d_diag256(float (*As)[129], float* sinv,
                                 float* __restrict__ Wf, int r0, int tid) {
    int r = tid & 127, half = tid >> 7;
    for (int p = 0; p < 16; ++p) {
        int j0 = p * 8;
        for (int j = j0; j < j0 + 8; ++j) {
            if (tid == j) {
                float d = sqrtf(As[j][j]);
                As[j][j] = d;
                sinv[j] = 1.0f / d;
            }
            __syncthreads();
            float arj = 0.0f;
            if (half == 0 && r > j) {
                arj = As[r][j] * sinv[j];
                As[r][j] = arj;
            }
            __syncthreads();
            if (half == 0 && r > j) {
#pragma unroll
                for (int c = j + 1; c < j0 + 8; ++c)
                    As[r][c] -= arj * As[c][j];
            }
        }
        __syncthreads();
        if (p < 15) {
            float a[8];
#pragma unroll
            for (int t = 0; t < 8; ++t) a[t] = As[r][j0 + t];
            for (int c = j0 + 8 + half; c < 128; c += 2) {
                if (r >= c) {
                    float s = As[r][c];
#pragma unroll
                    for (int t = 0; t < 8; ++t) s -= a[t] * As[c][j0 + t];
                    As[r][c] = s;
                }
            }
        }
        __syncthreads();
    }
    if (tid < 128) {
        int c = tid;
        for (int rb = 0; rb < 16; ++rb) {
            int r0b = rb * 8;
            if (c >= r0b + 8) continue;
            float s[8];
#pragma unroll
            for (int i = 0; i < 8; ++i) s[i] = 0.0f;
            for (int t = 0; t < r0b; ++t) {
                if (t >= c) {
                    float xt = (t == c) ? sinv[c] : As[c][t];
#pragma unroll
                    for (int i = 0; i < 8; ++i) s[i] += As[r0b + i][t] * xt;
                }
            }
            float xloc[8];
#pragma unroll
            for (int i = 0; i < 8; ++i) {
                int rr = r0b + i;
                float v = 0.0f;
                if (rr >= c) {
                    v = ((rr == c) ? 1.0f : 0.0f) - s[i];
#pragma unroll
                    for (int t2 = 0; t2 < i; ++t2) {
                        int tt = r0b + t2;
                        if (tt >= c) v -= As[rr][tt] * xloc[t2];
                    }
                    v *= sinv[rr];
                    if (rr > c) As[c][rr] = v;
                }
                xloc[i] = v;
            }
        }
    }
    __syncthreads();
    for (int idx = tid; idx < BS * BS; idx += 256) {
        int rr = idx >> 7, cc = idx & 127;
        if (rr >= cc)
            Wf[(size_t)(r0 + rr) * M_N + r0 + cc] = (rr == cc) ? sinv[rr] : As[cc][rr];
    }
}

// ---------------- step kb: trailing update + NEXT diag fused into block 0 -------------
__global__ __launch_bounds__(256) void kw_step(float* __restrict__ Kf,
                                               float* __restrict__ Wf,
                                               float* __restrict__ Lf, int kb) {
    __shared__ float SA[64][129];
    __shared__ float SB[64][129];
    __shared__ float Ast[64][17];
    __shared__ float Wst[16][128];
    __shared__ float As[128][129];
    __shared__ float sinv[128];
    int tid = threadIdx.x;
    int base = (kb + 1) * BS;
    int cb = kb * BS;
    int tx = tid & 15, ty = tid >> 4;
    int nt = (NBK - 1 - kb) * 2;
    int ntile = nt * (nt + 1) / 2;

    if (blockIdx.x == 0) {
        d_strip(Kf, Wf, cb, base, SA, Ast, Wst, tid);
        d_strip(Kf, Wf, cb, base + 64, SB, Ast, Wst, tid);
        __syncthreads();
#pragma unroll
        for (int qq = 0; qq < 3; ++qq) {
            int qy = (qq == 0) ? 0 : 1;
            int qx = (qq == 2) ? 1 : 0;
            float (*Sy)[129] = qy ? SB : SA;
            float (*Sx)[129] = qx ? SB : SA;
            float acc[4][4];
#pragma unroll
            for (int i = 0; i < 4; ++i)
#pragma unroll
                for (int j = 0; j < 4; ++j) acc[i][j] = 0.0f;
            for (int t = 0; t < 128; ++t) {
                float a[4], b[4];
#pragma unroll
                for (int i = 0; i < 4; ++i) a[i] = Sy[ty * 4 + i][t];
#pragma unroll
                for (int j = 0; j < 4; ++j) b[j] = Sx[tx * 4 + j][t];
#pragma unroll
                for (int i = 0; i < 4; ++i)
#pragma unroll
                    for (int j = 0; j < 4; ++j) acc[i][j] = fmaf(a[i], b[j], acc[i][j]);
            }
#pragma unroll
            for (int i = 0; i < 4; ++i)
#pragma unroll
                for (int j = 0; j < 4; ++j)
                    As[qy * 64 + ty * 4 + i][qx * 64 + tx * 4 + j] =
                        Kf[(size_t)(base + qy * 64 + ty * 4 + i) * M_N +
                           base + qx * 64 + tx * 4 + j] - acc[i][j];
        }
        for (int idx = tid; idx < 64 * 128; idx += 256) {
            int rr = idx >> 7, cc = idx & 127;
            Lf[(size_t)(base + rr) * M_N + cb + cc]      = SA[rr][cc];
            Lf[(size_t)(base + 64 + rr) * M_N + cb + cc] = SB[rr][cc];
        }
        __syncthreads();
        d_diag256(As, sinv, Wf, base, tid);
    } else {
        int vp = blockIdx.x + 2;
        if (vp >= ntile) return;   // grid padding
        int by = 0;
        while ((by + 1) * (by + 2) / 2 <= vp) ++by;
        int bx = vp - by * (by + 1) / 2;
        int gr0 = base + by * 64, gc0 = base + bx * 64;
        d_strip(Kf, Wf, cb, gr0, SA, Ast, Wst, tid);
        if (bx != by) d_strip(Kf, Wf, cb, gc0, SB, Ast, Wst, tid);
        float (*PB)[129] = (bx == by) ? SA : SB;
        __syncthreads();
        float acc[4][4];
#pragma unroll
        for (int i = 0; i < 4; ++i)
#pragma unroll
            for (int j = 0; j < 4; ++j) acc[i][j] = 0.0f;
        for (int t = 0; t < 128; ++t) {
            float a[4], b[4];
#pragma unroll
            for (int i = 0; i < 4; ++i) a[i] = SA[ty * 4 + i][t];
#pragma unroll
            for (int j = 0; j < 4; ++j) b[j] = PB[tx * 4 + j][t];
#pragma unroll
            for (int i = 0; i < 4; ++i)
#pragma unroll
                for (int j = 0; j < 4; ++j) acc[i][j] = fmaf(a[i], b[j], acc[i][j]);
        }
#pragma unroll
        for (int i = 0; i < 4; ++i)
#pragma unroll
            for (int j = 0; j < 4; ++j)
                Kf[(size_t)(gr0 + ty * 4 + i) * M_N + gc0 + tx * 4 + j] -= acc[i][j];
        if (by == bx) {
            for (int idx = tid; idx < 64 * 128; idx += 256)
                Lf[(size_t)(gr0 + (idx >> 7)) * M_N + cb + (idx & 127)] =
                    SA[idx >> 7][idx & 127];
        }
    }
}

// ---------------- trtri v2: right-looking, P in registers, barrier-free updates -------
// Block (j, ct): cols c0..c0+31 of column-block j. acc[pi][8] = P_{j+1+pi} rows rq.
__global__ __launch_bounds__(512) void kw_trtri(const float* __restrict__ Lf,
                                                float* __restrict__ Wf) {
    __shared__ float Pt[128][33];     // P_t staged for W_tt apply
    __shared__ float Wcur[128][33];   // current W_tj tile
    int j  = blockIdx.y;              // 0..6
    int ct = blockIdx.x;              // 0..3
    int c0 = j * BS + ct * 32;
    int tid = threadIdx.x;
    int rq = tid >> 2, cq = tid & 3;
    int cbase = cq * 8;

    float acc[7][8];
#pragma unroll
    for (int pi = 0; pi < 7; ++pi)
#pragma unroll
        for (int c = 0; c < 8; ++c) acc[pi][c] = 0.0f;

    for (int t = j; t < 8; ++t) {
        // ---- step A: obtain W_tj tile into Wcur ----
        if (t == j) {
            for (int idx = tid; idx < 128 * 32; idx += 512) {
                int rr = idx >> 5, cc = idx & 31;
                int gr = j * BS + rr, gc = c0 + cc;
                Wcur[rr][cc] = (gr >= gc) ? Wf[(size_t)gr * M_N + gc] : 0.0f;
            }
            __syncthreads();
        } else {
            int pt = t - j - 1;
            // spill P_t (regs) -> LDS; barrier also fences prior update's Wcur reads
#pragma unroll
            for (int pi = 0; pi < 7; ++pi)
                if (pi == pt) {
#pragma unroll
                    for (int c = 0; c < 8; ++c) Pt[rq][cbase + c] = acc[pi][c];
                }
            __syncthreads();
            // Wcur[r][c] = -sum_k W_tt[r][k] * Pt[k][c]   (W_tt lower-masked)
            float wv[8];
#pragma unroll
            for (int c = 0; c < 8; ++c) wv[c] = 0.0f;
            const float* wrow = Wf + (size_t)(t * BS + rq) * M_N + t * BS;
            for (int ch = 0; ch < 4; ++ch) {
                float l4[32];
#pragma unroll
                for (int u = 0; u < 8; ++u)
                    *(float4*)&l4[u * 4] = *(const float4*)&wrow[ch * 32 + u * 4];
#pragma unroll
                for (int kk = 0; kk < 32; ++kk) {
                    int k = ch * 32 + kk;
                    float lv = (k <= rq) ? l4[kk] : 0.0f;
#pragma unroll
                    for (int c = 0; c < 8; ++c)
                        wv[c] = fmaf(lv, Pt[k][cbase + c], wv[c]);
                }
            }
#pragma unroll
            for (int c = 0; c < 8; ++c) {
                float v = -wv[c];
                Wcur[rq][cbase + c] = v;
                Wf[(size_t)(t * BS + rq) * M_N + c0 + cbase + c] = v;
            }
            __syncthreads();
        }
        // ---- step B: P_i += L_it * W_tj for all i > t (barrier-free) ----
        if (t < 7) {
#pragma unroll
            for (int pi = 0; pi < 7; ++pi) {
                int i = j + 1 + pi;
                if (i <= 7 && i > t) {
                    const float* lrow = Lf + (size_t)(i * BS + rq) * M_N + t * BS;
                    for (int ch = 0; ch < 4; ++ch) {
                        float l4[32];
#pragma unroll
                        for (int u = 0; u < 8; ++u)
                            *(float4*)&l4[u * 4] = *(const float4*)&lrow[ch * 32 + u * 4];
#pragma unroll
                        for (int kk = 0; kk < 32; ++kk) {
#pragma unroll
                            for (int c = 0; c < 8; ++c)
                                acc[pi][c] = fmaf(l4[kk], Wcur[ch * 32 + kk][cbase + c],
                                                  acc[pi][c]);
                        }
                    }
                }
            }
        }
    }
}

// ---------------- pack W (fp32) into MFMA B-fragment order, fp16 hi/lo ----------------
__global__ void kw_pack(const float* __restrict__ Wf, _Float16* __restrict__ Wph,
                        _Float16* __restrict__ Wpl) {
    int T = blockIdx.x * 256 + threadIdx.x;
    int lane = T & 63, fid = T >> 6;
    int jn = fid & 63, kik = fid >> 6;
    int ki = kik & 3, kc = kik >> 2;
    int j  = jn * 16 + (lane & 15);
    int kb = kc * 128 + ki * 32 + (lane >> 4) * 8;
    f16x8 h, lo;
#pragma unroll
    for (int e = 0; e < 8; ++e) {
        int k = kb + e;
        float v = (k <= j) ? Wf[(size_t)j * M_N + k] : 0.0f;
        _Float16 hh = (_Float16)v;
        h[e]  = hh;
        lo[e] = (_Float16)(v - (float)hh);
    }
    size_t off = (size_t)fid * 512 + lane * 8;
    *(f16x8*)(Wph + off) = h;
    *(f16x8*)(Wpl + off) = lo;
}

// ---------------- main fused MFMA kernel: 32 rows x 1024 cols, FULL tile in LDS -------
// 64 KB LDS -> 2 blocks/CU; __launch_bounds__(512,4) requests 4 waves/EU.
__global__ __launch_bounds__(512, 4) void k_mm(const float* __restrict__ x_star,
                                               const float* __restrict__ pf,
                                               const float* __restrict__ Zst,
                                               const _Float16* __restrict__ Wph,
                                               const _Float16* __restrict__ Wpl,
                                               float* __restrict__ out, int Bq) {
    __shared__ __align__(16) char kls[32 * 2048];   // [row][1024 fp16], 16B-slot swizzled
    __shared__ float red_l[32];
    int tid  = threadIdx.x;
    int slab = blockIdx.x;
    int w = tid >> 6, lane = tid & 63;
    int lrow = lane & 15, kgrp = lane >> 4;

    int scc = tid & 15, srow = tid >> 4;
    int q0 = slab * 32 + srow;
    int qa = (q0 < Bq) ? q0 : (Bq - 1);
    float xa0 = x_star[(size_t)qa * 5 + 0] * pf[0];
    float xa1 = x_star[(size_t)qa * 5 + 1] * pf[1];
    float xa2 = x_star[(size_t)qa * 5 + 2] * pf[2];
    float xa3 = x_star[(size_t)qa * 5 + 3] * pf[3];
    float xa4 = x_star[(size_t)qa * 5 + 4] * pf[4];
    float pv = pf[5];
    if (tid < 32) red_l[tid] = 0.0f;

    int swz = (srow & 15) << 4;
    for (int kc = 0; kc < 8; ++kc) {
        f16x8 h0;
#pragma unroll
        for (int bb = 0; bb < 2; ++bb) {
            int lb = kc * 128 + scc * 8 + bb * 4;
            float z0[4], z1[4], z2[4], z3[4], z4[4];
            *(float4*)z0 = *(const float4*)&Zst[lb];
            *(float4*)z1 = *(const float4*)&Zst[M_N + lb];
            *(float4*)z2 = *(const float4*)&Zst[2 * M_N + lb];
            *(float4*)z3 = *(const float4*)&Zst[3 * M_N + lb];
            *(float4*)z4 = *(const float4*)&Zst[4 * M_N + lb];
#pragma unroll
            for (int e = 0; e < 4; ++e) {
                float dx0 = xa0 - z0[e], dx1 = xa1 - z1[e], dx2 = xa2 - z2[e],
                      dx3 = xa3 - z3[e], dx4 = xa4 - z4[e];
                float d2 = dx0 * dx0 + dx1 * dx1 + dx2 * dx2 + dx3 * dx3 + dx4 * dx4;
                float dd = d2 + 1e-8f;
                float dist = sqrtf(dd);
                float sv = 2.23606798f * dist;
                h0[bb * 4 + e] = (_Float16)(pv * (1.0f + sv + 1.66666667f * dd) * __expf(-sv));
            }
        }
        int cb = kc * 256 + scc * 16;
        *(f16x8*)(&kls[srow * 2048 + (cb ^ swz)]) = h0;
    }
    __syncthreads();                             // the ONE barrier

    for (int jg = 0; jg < 4; ++jg) {
        f32x4 acc[2][2];
#pragma unroll
        for (int mi = 0; mi < 2; ++mi)
#pragma unroll
            for (int nj = 0; nj < 2; ++nj) acc[mi][nj] = (f32x4)(0.0f);

        int jng_hi = jg * 16 + 8 + ((w + 1) & 7);
        int jmax_w = jng_hi * 16 + 15;

        for (int kt = 0; kt < 32; ++kt) {
            int kmin = kt * 32;
            if (kmin > jmax_w) break;
            f16x8 A_[2];
#pragma unroll
            for (int mi = 0; mi < 2; ++mi) {
                int row = mi * 16 + lrow;
                int cb  = kt * 64 + kgrp * 16;
                A_[mi] = *(const f16x8*)(&kls[row * 2048 + (cb ^ ((row & 15) << 4))]);
            }
#pragma unroll
            for (int nj = 0; nj < 2; ++nj) {
                int jng = jg * 16 + nj * 8 + ((w + nj) & 7);
                if (kmin > jng * 16 + 15) continue;
                size_t fo = ((size_t)(kt * 64 + jng)) * 512 + lane * 8;
                f16x8 Bh = *(const f16x8*)(Wph + fo);
                f16x8 Bl = *(const f16x8*)(Wpl + fo);
#pragma unroll
                for (int mi = 0; mi < 2; ++mi) {
                    acc[mi][nj] = __builtin_amdgcn_mfma_f32_16x16x32_f16(A_[mi], Bh, acc[mi][nj], 0, 0, 0);
                    acc[mi][nj] = __builtin_amdgcn_mfma_f32_16x16x32_f16(A_[mi], Bl, acc[mi][nj], 0, 0, 0);
                }
            }
        }
#pragma unroll
        for (int mi = 0; mi < 2; ++mi) {
#pragma unroll
            for (int q = 0; q < 4; ++q) {
                float s = 0.0f;
#pragma unroll
                for (int nj = 0; nj < 2; ++nj) s = fmaf(acc[mi][nj][q], acc[mi][nj][q], s);
                s += __shfl_xor(s, 1);
                s += __shfl_xor(s, 2);
                s += __shfl_xor(s, 4);
                s += __shfl_xor(s, 8);
                if (lrow == 0) atomicAdd(&red_l[mi * 16 + kgrp * 4 + q], s);
            }
        }
    }
    __syncthreads();
    if (tid < 32) {
        int b = slab * 32 + tid;
        if (b < Bq) out[b] = sqrtf(fmaxf(pv - red_l[tid], 1e-6f));
    }
}

extern "C" void kernel_launch(void* const* d_in, const int* in_sizes, int n_in,
                              void* d_out, int out_size, void* d_ws, size_t ws_size,
                              hipStream_t stream) {
    const float* x_star  = (const float*)d_in[0];
    const float* log_ls  = (const float*)d_in[1];
    const float* log_var = (const float*)d_in[2];
    const float* Z_raw   = (const float*)d_in[3];
    float* out = (float*)d_out;
    int Bq = in_sizes[0] / 5;

    char* ws = (char*)d_ws;
    float*     Kf  = (float*)(ws + OFF_KF);
    float*     Lf  = (float*)(ws + OFF_LF);
    float*     Wf  = (float*)(ws + OFF_WF);
    _Float16*  Wph = (_Float16*)(ws + OFF_WPH);
    _Float16*  Wpl = (_Float16*)(ws + OFF_WPL);
    float*     pf  = (float*)(ws + OFF_PF);
    float*     Zst = (float*)(ws + OFF_ZT);

    k_build<<<4096, 256, 0, stream>>>(log_ls, log_var, Z_raw, Kf, pf, Zst);
    kw_diag<<<64, 512, 0, stream>>>(Kf, Wf, 0);
    for (int kb = 0; kb < NBK - 1; ++kb) {
        int nt = (NBK - 1 - kb) * 2;
        int grid = nt * (nt + 1) / 2 - 2;
        if (grid < 64) grid = 64;                // tiny-grid stall mitigation
        kw_step<<<grid, 256, 0, stream>>>(Kf, Wf, Lf, kb);
    }
    kw_trtri<<<dim3(4, 7), 512, 0, stream>>>(Lf, Wf);
    kw_pack<<<512, 256, 0, stream>>>(Wf, Wph, Wpl);

    int slabs = (Bq + 31) / 32;
    k_mm<<<slabs, 512, 0, stream>>>(x_star, pf, Zst, Wph, Wpl, out, Bq);
}

// Round 17
// 3435.092 us; speedup vs baseline: 1.1068x; 1.1068x over previous
//
#include <hip/hip_runtime.h>
#include <math.h>

// Sizes fixed by the problem.
#define B_TOT 131072
#define M_N   1024
#define BS    128      // Cholesky block size
#define NBK   8        // M_N / BS

typedef float    f32x4 __attribute__((ext_vector_type(4)));
typedef _Float16 f16x8 __attribute__((ext_vector_type(8)));

// Workspace layout (bytes). Total ~17 MB.
enum : size_t {
    OFF_KF  = 0,                          // fp32 K (Schur-updated)  4 MB
    OFF_LF  = (size_t)4 << 20,            // fp32 L off-diag strips  4 MB
    OFF_WF  = (size_t)8 << 20,            // fp32 W = L^-1 (lower)   4 MB
    OFF_WPH = (size_t)12 << 20,           // fp16 W packed hi        2 MB
    OFF_WPL = (size_t)14 << 20,           // fp16 W packed lo        2 MB
    OFF_PF  = (size_t)16 << 20,           // fp32 params (6)
    OFF_ZT  = ((size_t)16 << 20) + 256,   // fp32 Zs_t [5][1024]     20 KB
};

__device__ __constant__ float c_zscale[5] = {0.15f, 0.1f, 0.05f, 800.0f, 20.0f};
__device__ __constant__ float c_zshift[5] = {0.0f, 0.0f, 0.0f, 600.0f, 5.0f};

// ---------------- fused: params + Zst + K = matern52 + jitter (fp32) ----------------
__global__ __launch_bounds__(256) void k_build(const float* __restrict__ log_ls,
                                               const float* __restrict__ log_var,
                                               const float* __restrict__ Zraw,
                                               float* __restrict__ Kf,
                                               float* __restrict__ pf,
                                               float* __restrict__ Zst) {
    __shared__ float ps[6];
    __shared__ float zsi[5];
    int tid = threadIdx.x;
    if (tid < 5) ps[tid] = 1.0f / (__expf(log_ls[tid]) + 1e-8f);
    if (tid == 5) ps[5] = __expf(log_var[0]);
    __syncthreads();
    int i = blockIdx.x >> 2;
    int j = (blockIdx.x & 3) * 256 + tid;
    if (tid < 5) zsi[tid] = (Zraw[i * 5 + tid] * c_zscale[tid] + c_zshift[tid]) * ps[tid];
    __syncthreads();
    float d2 = 0.0f;
#pragma unroll
    for (int d = 0; d < 5; ++d) {
        float zj = (Zraw[j * 5 + d] * c_zscale[d] + c_zshift[d]) * ps[d];
        float df = zsi[d] - zj;
        d2 += df * df;
    }
    float dd = d2 + 1e-8f;
    float dist = sqrtf(dd);
    float s = 2.23606798f * dist;
    float v = ps[5] * (1.0f + s + 1.66666667f * dd) * __expf(-s);
    if (i == j) v += 1e-4f;
    Kf[(size_t)i * M_N + j] = v;
    if (blockIdx.x < 4) {
        int m = blockIdx.x * 256 + tid;
#pragma unroll
        for (int d = 0; d < 5; ++d)
            Zst[d * M_N + m] = (Zraw[m * 5 + d] * c_zscale[d] + c_zshift[d]) * ps[d];
    }
    if (blockIdx.x == 4 && tid < 6) pf[tid] = ps[tid];
}

// ---------------- standalone Cholesky diag block kb=0 (r12-verified) ----------------
__global__ __launch_bounds__(512) void kw_diag(float* __restrict__ Kf,
                                               float* __restrict__ Wf, int kb) {
    if (blockIdx.x) return;   // grid padding (tiny-grid stall mitigation)
    __shared__ float As[128][129];
    __shared__ float sinv[128];
    int tid = threadIdx.x;
    int r0 = kb * BS;
    for (int idx = tid; idx < BS * BS; idx += 512) {
        int rr = idx >> 7, cc = idx & 127;
        As[rr][cc] = Kf[(size_t)(r0 + rr) * M_N + r0 + cc];
    }
    __syncthreads();

    int r = tid & 127, q = tid >> 7;
    for (int p = 0; p < 16; ++p) {
        int j0 = p * 8;
        for (int j = j0; j < j0 + 8; ++j) {
            if (tid == j) {
                float d = sqrtf(As[j][j]);
                As[j][j] = d;
                sinv[j] = 1.0f / d;
            }
            __syncthreads();
            float arj = 0.0f;
            if (q == 0 && r > j) {
                arj = As[r][j] * sinv[j];
                As[r][j] = arj;
            }
            __syncthreads();
            if (q == 0 && r > j) {
#pragma unroll
                for (int c = j + 1; c < j0 + 8; ++c)
                    As[r][c] -= arj * As[c][j];
            }
        }
        __syncthreads();
        if (p < 15) {
            float a[8];
#pragma unroll
            for (int t = 0; t < 8; ++t) a[t] = As[r][j0 + t];
            for (int c = j0 + 8 + q; c < 128; c += 4) {
                if (r >= c) {
                    float s = As[r][c];
#pragma unroll
                    for (int t = 0; t < 8; ++t) s -= a[t] * As[c][j0 + t];
                    As[r][c] = s;
                }
            }
        }
        __syncthreads();
    }

    if (tid < 128) {
        int c = tid;
        for (int rb = 0; rb < 16; ++rb) {
            int r0b = rb * 8;
            if (c >= r0b + 8) continue;
            float s[8];
#pragma unroll
            for (int i = 0; i < 8; ++i) s[i] = 0.0f;
            for (int t = 0; t < r0b; ++t) {
                if (t >= c) {
                    float xt = (t == c) ? sinv[c] : As[c][t];
#pragma unroll
                    for (int i = 0; i < 8; ++i) s[i] += As[r0b + i][t] * xt;
                }
            }
            float xloc[8];
#pragma unroll
            for (int i = 0; i < 8; ++i) {
                int rr = r0b + i;
                float v = 0.0f;
                if (rr >= c) {
                    v = ((rr == c) ? 1.0f : 0.0f) - s[i];
#pragma unroll
                    for (int t2 = 0; t2 < i; ++t2) {
                        int tt = r0b + t2;
                        if (tt >= c) v -= As[rr][tt] * xloc[t2];
                    }
                    v *= sinv[rr];
                    if (rr > c) As[c][rr] = v;
                }
                xloc[i] = v;
            }
        }
    }
    __syncthreads();
    for (int idx = tid; idx < BS * BS; idx += 512) {
        int rr = idx >> 7, cc = idx & 127;
        if (rr >= cc)
            Wf[(size_t)(r0 + rr) * M_N + r0 + cc] = (rr == cc) ? sinv[rr] : As[cc][rr];
    }
}

// ---------------- strip: S(64x128) = A21[row0..] * W11^T (fp32, into LDS) -------------
static __device__ void d_strip(const float* __restrict__ Kf, const float* __restrict__ Wf,
                               int cb, int row0, float (*S)[129],
                               float (*Ast)[17], float (*Wst)[128], int tid) {
    int c = tid & 127, q = tid >> 7;
    float acc[32];
#pragma unroll
    for (int i = 0; i < 32; ++i) acc[i] = 0.0f;
    for (int tc = 0; tc < 8; ++tc) {
        int tb = tc * 16;
        __syncthreads();
        for (int idx = tid; idx < 64 * 16; idx += 256) {
            int rr = idx >> 4, tt = idx & 15;
            Ast[rr][tt] = Kf[(size_t)(row0 + rr) * M_N + cb + tb + tt];
        }
        for (int idx = tid; idx < 128 * 16; idx += 256) {
            int cc = idx >> 4, tt = idx & 15;
            Wst[tt][cc] = (tb + tt <= cc) ? Wf[(size_t)(cb + cc) * M_N + cb + tb + tt] : 0.0f;
        }
        __syncthreads();
#pragma unroll
        for (int t = 0; t < 16; ++t) {
            float w = Wst[t][c];
#pragma unroll
            for (int i = 0; i < 32; ++i) acc[i] += Ast[q * 32 + i][t] * w;
        }
    }
    __syncthreads();
#pragma unroll
    for (int i = 0; i < 32; ++i) S[q * 32 + i][c] = acc[i];
}

// ---------------- diag factor + inverse, 256 threads (r12-verified) ----------------
static __device__ void d_diag256(float (*As)[129], float* sinv,
                                 float* __restrict__ Wf, int r0, int tid) {
    int r = tid & 127, half = tid >> 7;
    for (int p = 0; p < 16; ++p) {
        int j0 = p * 8;
        for (int j = j0; j < j0 + 8; ++j) {
            if (tid == j) {
                float d = sqrtf(As[j][j]);
                As[j][j] = d;
                sinv[j] = 1.0f / d;
            }
            __syncthreads();
            float arj = 0.0f;
            if (half == 0 && r > j) {
                arj = As[r][j] * sinv[j];
                As[r][j] = arj;
            }
            __syncthreads();
            if (half == 0 && r > j) {
#pragma unroll
                for (int c = j + 1; c < j0 + 8; ++c)
                    As[r][c] -= arj * As[c][j];
            }
        }
        __syncthreads();
        if (p < 15) {
            float a[8];
#pragma unroll
            for (int t = 0; t < 8; ++t) a[t] = As[r][j0 + t];
            for (int c = j0 + 8 + half; c < 128; c += 2) {
                if (r >= c) {
                    float s = As[r][c];
#pragma unroll
                    for (int t = 0; t < 8; ++t) s -= a[t] * As[c][j0 + t];
                    As[r][c] = s;
                }
            }
        }
        __syncthreads();
    }
    if (tid < 128) {
        int c = tid;
        for (int rb = 0; rb < 16; ++rb) {
            int r0b = rb * 8;
            if (c >= r0b + 8) continue;
            float s[8];
#pragma unroll
            for (int i = 0; i < 8; ++i) s[i] = 0.0f;
            for (int t = 0; t < r0b; ++t) {
                if (t >= c) {
                    float xt = (t == c) ? sinv[c] : As[c][t];
#pragma unroll
                    for (int i = 0; i < 8; ++i) s[i] += As[r0b + i][t] * xt;
                }
            }
            float xloc[8];
#pragma unroll
            for (int i = 0; i < 8; ++i) {
                int rr = r0b + i;
                float v = 0.0f;
                if (rr >= c) {
                    v = ((rr == c) ? 1.0f : 0.0f) - s[i];
#pragma unroll
                    for (int t2 = 0; t2 < i; ++t2) {
                        int tt = r0b + t2;
                        if (tt >= c) v -= As[rr][tt] * xloc[t2];
                    }
                    v *= sinv[rr];
                    if (rr > c) As[c][rr] = v;
                }
                xloc[i] = v;
            }
        }
    }
    __syncthreads();
    for (int idx = tid; idx < BS * BS; idx += 256) {
        int rr = idx >> 7, cc = idx & 127;
        if (rr >= cc)
            Wf[(size_t)(r0 + rr) * M_N + r0 + cc] = (rr == cc) ? sinv[rr] : As[cc][rr];
    }
}

// ---------------- step kb: trailing update + NEXT diag fused into block 0 -------------
__global__ __launch_bounds__(256) void kw_step(float* __restrict__ Kf,
                                               float* __restrict__ Wf,
                                               float* __restrict__ Lf, int kb) {
    __shared__ float SA[64][129];
    __shared__ float SB[64][129];
    __shared__ float Ast[64][17];
    __shared__ float Wst[16][128];
    __shared__ float As[128][129];
    __shared__ float sinv[128];
    int tid = threadIdx.x;
    int base = (kb + 1) * BS;
    int cb = kb * BS;
    int tx = tid & 15, ty = tid >> 4;
    int nt = (NBK - 1 - kb) * 2;
    int ntile = nt * (nt + 1) / 2;

    if (blockIdx.x == 0) {
        d_strip(Kf, Wf, cb, base, SA, Ast, Wst, tid);
        d_strip(Kf, Wf, cb, base + 64, SB, Ast, Wst, tid);
        __syncthreads();
#pragma unroll
        for (int qq = 0; qq < 3; ++qq) {
            int qy = (qq == 0) ? 0 : 1;
            int qx = (qq == 2) ? 1 : 0;
            float (*Sy)[129] = qy ? SB : SA;
            float (*Sx)[129] = qx ? SB : SA;
            float acc[4][4];
#pragma unroll
            for (int i = 0; i < 4; ++i)
#pragma unroll
                for (int j = 0; j < 4; ++j) acc[i][j] = 0.0f;
            for (int t = 0; t < 128; ++t) {
                float a[4], b[4];
#pragma unroll
                for (int i = 0; i < 4; ++i) a[i] = Sy[ty * 4 + i][t];
#pragma unroll
                for (int j = 0; j < 4; ++j) b[j] = Sx[tx * 4 + j][t];
#pragma unroll
                for (int i = 0; i < 4; ++i)
#pragma unroll
                    for (int j = 0; j < 4; ++j) acc[i][j] = fmaf(a[i], b[j], acc[i][j]);
            }
#pragma unroll
            for (int i = 0; i < 4; ++i)
#pragma unroll
                for (int j = 0; j < 4; ++j)
                    As[qy * 64 + ty * 4 + i][qx * 64 + tx * 4 + j] =
                        Kf[(size_t)(base + qy * 64 + ty * 4 + i) * M_N +
                           base + qx * 64 + tx * 4 + j] - acc[i][j];
        }
        for (int idx = tid; idx < 64 * 128; idx += 256) {
            int rr = idx >> 7, cc = idx & 127;
            Lf[(size_t)(base + rr) * M_N + cb + cc]      = SA[rr][cc];
            Lf[(size_t)(base + 64 + rr) * M_N + cb + cc] = SB[rr][cc];
        }
        __syncthreads();
        d_diag256(As, sinv, Wf, base, tid);
    } else {
        int vp = blockIdx.x + 2;
        if (vp >= ntile) return;   // grid padding
        int by = 0;
        while ((by + 1) * (by + 2) / 2 <= vp) ++by;
        int bx = vp - by * (by + 1) / 2;
        int gr0 = base + by * 64, gc0 = base + bx * 64;
        d_strip(Kf, Wf, cb, gr0, SA, Ast, Wst, tid);
        if (bx != by) d_strip(Kf, Wf, cb, gc0, SB, Ast, Wst, tid);
        float (*PB)[129] = (bx == by) ? SA : SB;
        __syncthreads();
        float acc[4][4];
#pragma unroll
        for (int i = 0; i < 4; ++i)
#pragma unroll
            for (int j = 0; j < 4; ++j) acc[i][j] = 0.0f;
        for (int t = 0; t < 128; ++t) {
            float a[4], b[4];
#pragma unroll
            for (int i = 0; i < 4; ++i) a[i] = SA[ty * 4 + i][t];
#pragma unroll
            for (int j = 0; j < 4; ++j) b[j] = PB[tx * 4 + j][t];
#pragma unroll
            for (int i = 0; i < 4; ++i)
#pragma unroll
                for (int j = 0; j < 4; ++j) acc[i][j] = fmaf(a[i], b[j], acc[i][j]);
        }
#pragma unroll
        for (int i = 0; i < 4; ++i)
#pragma unroll
            for (int j = 0; j < 4; ++j)
                Kf[(size_t)(gr0 + ty * 4 + i) * M_N + gc0 + tx * 4 + j] -= acc[i][j];
        if (by == bx) {
            for (int idx = tid; idx < 64 * 128; idx += 256)
                Lf[(size_t)(gr0 + (idx >> 7)) * M_N + cb + (idx & 127)] =
                    SA[idx >> 7][idx & 127];
        }
    }
}

// ---------------- trtri v3: right-looking, P in regs (16 cols/block, no spill) --------
// Block (j, ct): cols c0..c0+15 of column-block j. acc[pi][4] = P_{j+1+pi} row rq.
__global__ __launch_bounds__(512) void kw_trtri(const float* __restrict__ Lf,
                                                float* __restrict__ Wf) {
    __shared__ float Pt[128][17];     // P_t staged for W_tt apply
    __shared__ float Wcur[128][17];   // current W_tj tile
    int j  = blockIdx.y;              // 0..6
    int ct = blockIdx.x;              // 0..7
    int c0 = j * BS + ct * 16;
    int tid = threadIdx.x;
    int rq = tid >> 2, cq = tid & 3;
    int cbase = cq * 4;

    float acc[7][4];
#pragma unroll
    for (int pi = 0; pi < 7; ++pi)
#pragma unroll
        for (int c = 0; c < 4; ++c) acc[pi][c] = 0.0f;

    for (int t = j; t < 8; ++t) {
        // ---- step A: obtain W_tj tile into Wcur ----
        if (t == j) {
            for (int idx = tid; idx < 128 * 16; idx += 512) {
                int rr = idx >> 4, cc = idx & 15;
                int gr = j * BS + rr, gc = c0 + cc;
                Wcur[rr][cc] = (gr >= gc) ? Wf[(size_t)gr * M_N + gc] : 0.0f;
            }
            __syncthreads();
        } else {
            int pt = t - j - 1;
            // spill P_t (regs) -> LDS; barrier also fences prior update's Wcur reads
#pragma unroll
            for (int pi = 0; pi < 7; ++pi)
                if (pi == pt) {
#pragma unroll
                    for (int c = 0; c < 4; ++c) Pt[rq][cbase + c] = acc[pi][c];
                }
            __syncthreads();
            // Wcur[r][c] = -sum_k W_tt[r][k] * Pt[k][c]   (W_tt lower-masked)
            float wv[4];
#pragma unroll
            for (int c = 0; c < 4; ++c) wv[c] = 0.0f;
            const float* wrow = Wf + (size_t)(t * BS + rq) * M_N + t * BS;
            for (int ch = 0; ch < 16; ++ch) {
                float l8[8];
                *(float4*)&l8[0] = *(const float4*)&wrow[ch * 8];
                *(float4*)&l8[4] = *(const float4*)&wrow[ch * 8 + 4];
#pragma unroll
                for (int kk = 0; kk < 8; ++kk) {
                    int k = ch * 8 + kk;
                    float lv = (k <= rq) ? l8[kk] : 0.0f;
#pragma unroll
                    for (int c = 0; c < 4; ++c)
                        wv[c] = fmaf(lv, Pt[k][cbase + c], wv[c]);
                }
            }
#pragma unroll
            for (int c = 0; c < 4; ++c) {
                float v = -wv[c];
                Wcur[rq][cbase + c] = v;
                Wf[(size_t)(t * BS + rq) * M_N + c0 + cbase + c] = v;
            }
            __syncthreads();
        }
        // ---- step B: P_i += L_it * W_tj for all i > t (barrier-free) ----
        if (t < 7) {
#pragma unroll
            for (int pi = 0; pi < 7; ++pi) {
                int i = j + 1 + pi;
                if (i <= 7 && i > t) {
                    const float* lrow = Lf + (size_t)(i * BS + rq) * M_N + t * BS;
                    for (int ch = 0; ch < 16; ++ch) {
                        float l8[8];
                        *(float4*)&l8[0] = *(const float4*)&lrow[ch * 8];
                        *(float4*)&l8[4] = *(const float4*)&lrow[ch * 8 + 4];
#pragma unroll
                        for (int kk = 0; kk < 8; ++kk) {
#pragma unroll
                            for (int c = 0; c < 4; ++c)
                                acc[pi][c] = fmaf(l8[kk], Wcur[ch * 8 + kk][cbase + c],
                                                  acc[pi][c]);
                        }
                    }
                }
            }
        }
    }
}

// ---------------- pack W (fp32) into MFMA B-fragment order, fp16 hi/lo ----------------
__global__ void kw_pack(const float* __restrict__ Wf, _Float16* __restrict__ Wph,
                        _Float16* __restrict__ Wpl) {
    int T = blockIdx.x * 256 + threadIdx.x;
    int lane = T & 63, fid = T >> 6;
    int jn = fid & 63, kik = fid >> 6;
    int ki = kik & 3, kc = kik >> 2;
    int j  = jn * 16 + (lane & 15);
    int kb = kc * 128 + ki * 32 + (lane >> 4) * 8;
    f16x8 h, lo;
#pragma unroll
    for (int e = 0; e < 8; ++e) {
        int k = kb + e;
        float v = (k <= j) ? Wf[(size_t)j * M_N + k] : 0.0f;
        _Float16 hh = (_Float16)v;
        h[e]  = hh;
        lo[e] = (_Float16)(v - (float)hh);
    }
    size_t off = (size_t)fid * 512 + lane * 8;
    *(f16x8*)(Wph + off) = h;
    *(f16x8*)(Wpl + off) = lo;
}

// ---------------- main fused MFMA kernel: 32 rows x 1024 cols, FULL tile in LDS -------
// 64 KB LDS -> 2 blocks/CU; __launch_bounds__(512,4) requests 4 waves/EU.
__global__ __launch_bounds__(512, 4) void k_mm(const float* __restrict__ x_star,
                                               const float* __restrict__ pf,
                                               const float* __restrict__ Zst,
                                               const _Float16* __restrict__ Wph,
                                               const _Float16* __restrict__ Wpl,
                                               float* __restrict__ out, int Bq) {
    __shared__ __align__(16) char kls[32 * 2048];   // [row][1024 fp16], 16B-slot swizzled
    __shared__ float red_l[32];
    int tid  = threadIdx.x;
    int slab = blockIdx.x;
    int w = tid >> 6, lane = tid & 63;
    int lrow = lane & 15, kgrp = lane >> 4;

    int scc = tid & 15, srow = tid >> 4;
    int q0 = slab * 32 + srow;
    int qa = (q0 < Bq) ? q0 : (Bq - 1);
    float xa0 = x_star[(size_t)qa * 5 + 0] * pf[0];
    float xa1 = x_star[(size_t)qa * 5 + 1] * pf[1];
    float xa2 = x_star[(size_t)qa * 5 + 2] * pf[2];
    float xa3 = x_star[(size_t)qa * 5 + 3] * pf[3];
    float xa4 = x_star[(size_t)qa * 5 + 4] * pf[4];
    float pv = pf[5];
    if (tid < 32) red_l[tid] = 0.0f;

    int swz = (srow & 15) << 4;
    for (int kc = 0; kc < 8; ++kc) {
        f16x8 h0;
#pragma unroll
        for (int bb = 0; bb < 2; ++bb) {
            int lb = kc * 128 + scc * 8 + bb * 4;
            float z0[4], z1[4], z2[4], z3[4], z4[4];
            *(float4*)z0 = *(const float4*)&Zst[lb];
            *(float4*)z1 = *(const float4*)&Zst[M_N + lb];
            *(float4*)z2 = *(const float4*)&Zst[2 * M_N + lb];
            *(float4*)z3 = *(const float4*)&Zst[3 * M_N + lb];
            *(float4*)z4 = *(const float4*)&Zst[4 * M_N + lb];
#pragma unroll
            for (int e = 0; e < 4; ++e) {
                float dx0 = xa0 - z0[e], dx1 = xa1 - z1[e], dx2 = xa2 - z2[e],
                      dx3 = xa3 - z3[e], dx4 = xa4 - z4[e];
                float d2 = dx0 * dx0 + dx1 * dx1 + dx2 * dx2 + dx3 * dx3 + dx4 * dx4;
                float dd = d2 + 1e-8f;
                float dist = sqrtf(dd);
                float sv = 2.23606798f * dist;
                h0[bb * 4 + e] = (_Float16)(pv * (1.0f + sv + 1.66666667f * dd) * __expf(-sv));
            }
        }
        int cb = kc * 256 + scc * 16;
        *(f16x8*)(&kls[srow * 2048 + (cb ^ swz)]) = h0;
    }
    __syncthreads();                             // the ONE barrier

    for (int jg = 0; jg < 4; ++jg) {
        f32x4 acc[2][2];
#pragma unroll
        for (int mi = 0; mi < 2; ++mi)
#pragma unroll
            for (int nj = 0; nj < 2; ++nj) acc[mi][nj] = (f32x4)(0.0f);

        int jng_hi = jg * 16 + 8 + ((w + 1) & 7);
        int jmax_w = jng_hi * 16 + 15;

        for (int kt = 0; kt < 32; ++kt) {
            int kmin = kt * 32;
            if (kmin > jmax_w) break;
            f16x8 A_[2];
#pragma unroll
            for (int mi = 0; mi < 2; ++mi) {
                int row = mi * 16 + lrow;
                int cb  = kt * 64 + kgrp * 16;
                A_[mi] = *(const f16x8*)(&kls[row * 2048 + (cb ^ ((row & 15) << 4))]);
            }
#pragma unroll
            for (int nj = 0; nj < 2; ++nj) {
                int jng = jg * 16 + nj * 8 + ((w + nj) & 7);
                if (kmin > jng * 16 + 15) continue;
                size_t fo = ((size_t)(kt * 64 + jng)) * 512 + lane * 8;
                f16x8 Bh = *(const f16x8*)(Wph + fo);
                f16x8 Bl = *(const f16x8*)(Wpl + fo);
#pragma unroll
                for (int mi = 0; mi < 2; ++mi) {
                    acc[mi][nj] = __builtin_amdgcn_mfma_f32_16x16x32_f16(A_[mi], Bh, acc[mi][nj], 0, 0, 0);
                    acc[mi][nj] = __builtin_amdgcn_mfma_f32_16x16x32_f16(A_[mi], Bl, acc[mi][nj], 0, 0, 0);
                }
            }
        }
#pragma unroll
        for (int mi = 0; mi < 2; ++mi) {
#pragma unroll
            for (int q = 0; q < 4; ++q) {
                float s = 0.0f;
#pragma unroll
                for (int nj = 0; nj < 2; ++nj) s = fmaf(acc[mi][nj][q], acc[mi][nj][q], s);
                s += __shfl_xor(s, 1);
                s += __shfl_xor(s, 2);
                s += __shfl_xor(s, 4);
                s += __shfl_xor(s, 8);
                if (lrow == 0) atomicAdd(&red_l[mi * 16 + kgrp * 4 + q], s);
            }
        }
    }
    __syncthreads();
    if (tid < 32) {
        int b = slab * 32 + tid;
        if (b < Bq) out[b] = sqrtf(fmaxf(pv - red_l[tid], 1e-6f));
    }
}

extern "C" void kernel_launch(void* const* d_in, const int* in_sizes, int n_in,
                              void* d_out, int out_size, void* d_ws, size_t ws_size,
                              hipStream_t stream) {
    const float* x_star  = (const float*)d_in[0];
    const float* log_ls  = (const float*)d_in[1];
    const float* log_var = (const float*)d_in[2];
    const float* Z_raw   = (const float*)d_in[3];
    float* out = (float*)d_out;
    int Bq = in_sizes[0] / 5;

    char* ws = (char*)d_ws;
    float*     Kf  = (float*)(ws + OFF_KF);
    float*     Lf  = (float*)(ws + OFF_LF);
    float*     Wf  = (float*)(ws + OFF_WF);
    _Float16*  Wph = (_Float16*)(ws + OFF_WPH);
    _Float16*  Wpl = (_Float16*)(ws + OFF_WPL);
    float*     pf  = (float*)(ws + OFF_PF);
    float*     Zst = (float*)(ws + OFF_ZT);

    k_build<<<4096, 256, 0, stream>>>(log_ls, log_var, Z_raw, Kf, pf, Zst);
    kw_diag<<<64, 512, 0, stream>>>(Kf, Wf, 0);
    for (int kb = 0; kb < NBK - 1; ++kb) {
        int nt = (NBK - 1 - kb) * 2;
        int grid = nt * (nt + 1) / 2 - 2;
        if (grid < 64) grid = 64;                // tiny-grid stall mitigation
        kw_step<<<grid, 256, 0, stream>>>(Kf, Wf, Lf, kb);
    }
    kw_trtri<<<dim3(8, 7), 512, 0, stream>>>(Lf, Wf);
    kw_pack<<<512, 256, 0, stream>>>(Wf, Wph, Wpl);

    int slabs = (Bq + 31) / 32;
    k_mm<<<slabs, 512, 0, stream>>>(x_star, pf, Zst, Wph, Wpl, out, Bq);
}

// Round 18
// 3038.510 us; speedup vs baseline: 1.2512x; 1.1305x over previous
//
#include <hip/hip_runtime.h>
#include <math.h>

// Sizes fixed by the problem.
#define B_TOT 131072
#define M_N   1024
#define BS    128      // Cholesky block size
#define NBK   8        // M_N / BS

typedef float    f32x4 __attribute__((ext_vector_type(4)));
typedef _Float16 f16x8 __attribute__((ext_vector_type(8)));

// Workspace layout (bytes). Total ~17 MB.
enum : size_t {
    OFF_KF  = 0,                          // fp32 K (Schur-updated)  4 MB
    OFF_LF  = (size_t)4 << 20,            // fp32 L off-diag strips  4 MB
    OFF_WF  = (size_t)8 << 20,            // fp32 W = L^-1 (lower)   4 MB
    OFF_WPH = (size_t)12 << 20,           // fp16 W packed hi        2 MB
    OFF_WPL = (size_t)14 << 20,           // fp16 W packed lo        2 MB
    OFF_PF  = (size_t)16 << 20,           // fp32 params (6)
    OFF_ZT  = ((size_t)16 << 20) + 256,   // fp32 Zs_t [5][1024]     20 KB
};

__device__ __constant__ float c_zscale[5] = {0.15f, 0.1f, 0.05f, 800.0f, 20.0f};
__device__ __constant__ float c_zshift[5] = {0.0f, 0.0f, 0.0f, 600.0f, 5.0f};

// ---------------- fused: params + Zst + K = matern52 + jitter (fp32) ----------------
__global__ __launch_bounds__(256) void k_build(const float* __restrict__ log_ls,
                                               const float* __restrict__ log_var,
                                               const float* __restrict__ Zraw,
                                               float* __restrict__ Kf,
                                               float* __restrict__ pf,
                                               float* __restrict__ Zst) {
    __shared__ float ps[6];
    __shared__ float zsi[5];
    int tid = threadIdx.x;
    if (tid < 5) ps[tid] = 1.0f / (__expf(log_ls[tid]) + 1e-8f);
    if (tid == 5) ps[5] = __expf(log_var[0]);
    __syncthreads();
    int i = blockIdx.x >> 2;
    int j = (blockIdx.x & 3) * 256 + tid;
    if (tid < 5) zsi[tid] = (Zraw[i * 5 + tid] * c_zscale[tid] + c_zshift[tid]) * ps[tid];
    __syncthreads();
    float d2 = 0.0f;
#pragma unroll
    for (int d = 0; d < 5; ++d) {
        float zj = (Zraw[j * 5 + d] * c_zscale[d] + c_zshift[d]) * ps[d];
        float df = zsi[d] - zj;
        d2 += df * df;
    }
    float dd = d2 + 1e-8f;
    float dist = sqrtf(dd);
    float s = 2.23606798f * dist;
    float v = ps[5] * (1.0f + s + 1.66666667f * dd) * __expf(-s);
    if (i == j) v += 1e-4f;
    Kf[(size_t)i * M_N + j] = v;
    if (blockIdx.x < 4) {
        int m = blockIdx.x * 256 + tid;
#pragma unroll
        for (int d = 0; d < 5; ++d)
            Zst[d * M_N + m] = (Zraw[m * 5 + d] * c_zscale[d] + c_zshift[d]) * ps[d];
    }
    if (blockIdx.x == 4 && tid < 6) pf[tid] = ps[tid];
}

// ---------------- standalone Cholesky diag block kb=0 (r12-verified) ----------------
__global__ __launch_bounds__(512) void kw_diag(float* __restrict__ Kf,
                                               float* __restrict__ Wf, int kb) {
    if (blockIdx.x) return;   // grid padding (tiny-grid stall mitigation)
    __shared__ float As[128][129];
    __shared__ float sinv[128];
    int tid = threadIdx.x;
    int r0 = kb * BS;
    for (int idx = tid; idx < BS * BS; idx += 512) {
        int rr = idx >> 7, cc = idx & 127;
        As[rr][cc] = Kf[(size_t)(r0 + rr) * M_N + r0 + cc];
    }
    __syncthreads();

    int r = tid & 127, q = tid >> 7;
    for (int p = 0; p < 16; ++p) {
        int j0 = p * 8;
        for (int j = j0; j < j0 + 8; ++j) {
            if (tid == j) {
                float d = sqrtf(As[j][j]);
                As[j][j] = d;
                sinv[j] = 1.0f / d;
            }
            __syncthreads();
            float arj = 0.0f;
            if (q == 0 && r > j) {
                arj = As[r][j] * sinv[j];
                As[r][j] = arj;
            }
            __syncthreads();
            if (q == 0 && r > j) {
#pragma unroll
                for (int c = j + 1; c < j0 + 8; ++c)
                    As[r][c] -= arj * As[c][j];
            }
        }
        __syncthreads();
        if (p < 15) {
            float a[8];
#pragma unroll
            for (int t = 0; t < 8; ++t) a[t] = As[r][j0 + t];
            for (int c = j0 + 8 + q; c < 128; c += 4) {
                if (r >= c) {
                    float s = As[r][c];
#pragma unroll
                    for (int t = 0; t < 8; ++t) s -= a[t] * As[c][j0 + t];
                    As[r][c] = s;
                }
            }
        }
        __syncthreads();
    }

    if (tid < 128) {
        int c = tid;
        for (int rb = 0; rb < 16; ++rb) {
            int r0b = rb * 8;
            if (c >= r0b + 8) continue;
            float s[8];
#pragma unroll
            for (int i = 0; i < 8; ++i) s[i] = 0.0f;
            for (int t = 0; t < r0b; ++t) {
                if (t >= c) {
                    float xt = (t == c) ? sinv[c] : As[c][t];
#pragma unroll
                    for (int i = 0; i < 8; ++i) s[i] += As[r0b + i][t] * xt;
                }
            }
            float xloc[8];
#pragma unroll
            for (int i = 0; i < 8; ++i) {
                int rr = r0b + i;
                float v = 0.0f;
                if (rr >= c) {
                    v = ((rr == c) ? 1.0f : 0.0f) - s[i];
#pragma unroll
                    for (int t2 = 0; t2 < i; ++t2) {
                        int tt = r0b + t2;
                        if (tt >= c) v -= As[rr][tt] * xloc[t2];
                    }
                    v *= sinv[rr];
                    if (rr > c) As[c][rr] = v;
                }
                xloc[i] = v;
            }
        }
    }
    __syncthreads();
    for (int idx = tid; idx < BS * BS; idx += 512) {
        int rr = idx >> 7, cc = idx & 127;
        if (rr >= cc)
            Wf[(size_t)(r0 + rr) * M_N + r0 + cc] = (rr == cc) ? sinv[rr] : As[cc][rr];
    }
}

// ---------------- strip: S(64x128) = A21[row0..] * W11^T (fp32, into LDS) -------------
static __device__ void d_strip(const float* __restrict__ Kf, const float* __restrict__ Wf,
                               int cb, int row0, float (*S)[129],
                               float (*Ast)[17], float (*Wst)[128], int tid) {
    int c = tid & 127, q = tid >> 7;
    float acc[32];
#pragma unroll
    for (int i = 0; i < 32; ++i) acc[i] = 0.0f;
    for (int tc = 0; tc < 8; ++tc) {
        int tb = tc * 16;
        __syncthreads();
        for (int idx = tid; idx < 64 * 16; idx += 256) {
            int rr = idx >> 4, tt = idx & 15;
            Ast[rr][tt] = Kf[(size_t)(row0 + rr) * M_N + cb + tb + tt];
        }
        for (int idx = tid; idx < 128 * 16; idx += 256) {
            int cc = idx >> 4, tt = idx & 15;
            Wst[tt][cc] = (tb + tt <= cc) ? Wf[(size_t)(cb + cc) * M_N + cb + tb + tt] : 0.0f;
        }
        __syncthreads();
#pragma unroll
        for (int t = 0; t < 16; ++t) {
            float w = Wst[t][c];
#pragma unroll
            for (int i = 0; i < 32; ++i) acc[i] += Ast[q * 32 + i][t] * w;
        }
    }
    __syncthreads();
#pragma unroll
    for (int i = 0; i < 32; ++i) S[q * 32 + i][c] = acc[i];
}

// ---------------- diag factor + inverse, 256 threads (r12-verified) ----------------
static __device__ void d_diag256(float (*As)[129], float* sinv,
                                 float* __restrict__ Wf, int r0, int tid) {
    int r = tid & 127, half = tid >> 7;
    for (int p = 0; p < 16; ++p) {
        int j0 = p * 8;
        for (int j = j0; j < j0 + 8; ++j) {
            if (tid == j) {
                float d = sqrtf(As[j][j]);
                As[j][j] = d;
                sinv[j] = 1.0f / d;
            }
            __syncthreads();
            float arj = 0.0f;
            if (half == 0 && r > j) {
                arj = As[r][j] * sinv[j];
                As[r][j] = arj;
            }
            __syncthreads();
            if (half == 0 && r > j) {
#pragma unroll
                for (int c = j + 1; c < j0 + 8; ++c)
                    As[r][c] -= arj * As[c][j];
            }
        }
        __syncthreads();
        if (p < 15) {
            float a[8];
#pragma unroll
            for (int t = 0; t < 8; ++t) a[t] = As[r][j0 + t];
            for (int c = j0 + 8 + half; c < 128; c += 2) {
                if (r >= c) {
                    float s = As[r][c];
#pragma unroll
                    for (int t = 0; t < 8; ++t) s -= a[t] * As[c][j0 + t];
                    As[r][c] = s;
                }
            }
        }
        __syncthreads();
    }
    if (tid < 128) {
        int c = tid;
        for (int rb = 0; rb < 16; ++rb) {
            int r0b = rb * 8;
            if (c >= r0b + 8) continue;
            float s[8];
#pragma unroll
            for (int i = 0; i < 8; ++i) s[i] = 0.0f;
            for (int t = 0; t < r0b; ++t) {
                if (t >= c) {
                    float xt = (t == c) ? sinv[c] : As[c][t];
#pragma unroll
                    for (int i = 0; i < 8; ++i) s[i] += As[r0b + i][t] * xt;
                }
            }
            float xloc[8];
#pragma unroll
            for (int i = 0; i < 8; ++i) {
                int rr = r0b + i;
                float v = 0.0f;
                if (rr >= c) {
                    v = ((rr == c) ? 1.0f : 0.0f) - s[i];
#pragma unroll
                    for (int t2 = 0; t2 < i; ++t2) {
                        int tt = r0b + t2;
                        if (tt >= c) v -= As[rr][tt] * xloc[t2];
                    }
                    v *= sinv[rr];
                    if (rr > c) As[c][rr] = v;
                }
                xloc[i] = v;
            }
        }
    }
    __syncthreads();
    for (int idx = tid; idx < BS * BS; idx += 256) {
        int rr = idx >> 7, cc = idx & 127;
        if (rr >= cc)
            Wf[(size_t)(r0 + rr) * M_N + r0 + cc] = (rr == cc) ? sinv[rr] : As[cc][rr];
    }
}

// ---------------- step kb: trailing update + NEXT diag fused into block 0 -------------
__global__ __launch_bounds__(256) void kw_step(float* __restrict__ Kf,
                                               float* __restrict__ Wf,
                                               float* __restrict__ Lf, int kb) {
    __shared__ float SA[64][129];
    __shared__ float SB[64][129];
    __shared__ float Ast[64][17];
    __shared__ float Wst[16][128];
    __shared__ float As[128][129];
    __shared__ float sinv[128];
    int tid = threadIdx.x;
    int base = (kb + 1) * BS;
    int cb = kb * BS;
    int tx = tid & 15, ty = tid >> 4;
    int nt = (NBK - 1 - kb) * 2;
    int ntile = nt * (nt + 1) / 2;

    if (blockIdx.x == 0) {
        d_strip(Kf, Wf, cb, base, SA, Ast, Wst, tid);
        d_strip(Kf, Wf, cb, base + 64, SB, Ast, Wst, tid);
        __syncthreads();
#pragma unroll
        for (int qq = 0; qq < 3; ++qq) {
            int qy = (qq == 0) ? 0 : 1;
            int qx = (qq == 2) ? 1 : 0;
            float (*Sy)[129] = qy ? SB : SA;
            float (*Sx)[129] = qx ? SB : SA;
            float acc[4][4];
#pragma unroll
            for (int i = 0; i < 4; ++i)
#pragma unroll
                for (int j = 0; j < 4; ++j) acc[i][j] = 0.0f;
            for (int t = 0; t < 128; ++t) {
                float a[4], b[4];
#pragma unroll
                for (int i = 0; i < 4; ++i) a[i] = Sy[ty * 4 + i][t];
#pragma unroll
                for (int j = 0; j < 4; ++j) b[j] = Sx[tx * 4 + j][t];
#pragma unroll
                for (int i = 0; i < 4; ++i)
#pragma unroll
                    for (int j = 0; j < 4; ++j) acc[i][j] = fmaf(a[i], b[j], acc[i][j]);
            }
#pragma unroll
            for (int i = 0; i < 4; ++i)
#pragma unroll
                for (int j = 0; j < 4; ++j)
                    As[qy * 64 + ty * 4 + i][qx * 64 + tx * 4 + j] =
                        Kf[(size_t)(base + qy * 64 + ty * 4 + i) * M_N +
                           base + qx * 64 + tx * 4 + j] - acc[i][j];
        }
        for (int idx = tid; idx < 64 * 128; idx += 256) {
            int rr = idx >> 7, cc = idx & 127;
            Lf[(size_t)(base + rr) * M_N + cb + cc]      = SA[rr][cc];
            Lf[(size_t)(base + 64 + rr) * M_N + cb + cc] = SB[rr][cc];
        }
        __syncthreads();
        d_diag256(As, sinv, Wf, base, tid);
    } else {
        int vp = blockIdx.x + 2;
        if (vp >= ntile) return;   // grid padding
        int by = 0;
        while ((by + 1) * (by + 2) / 2 <= vp) ++by;
        int bx = vp - by * (by + 1) / 2;
        int gr0 = base + by * 64, gc0 = base + bx * 64;
        d_strip(Kf, Wf, cb, gr0, SA, Ast, Wst, tid);
        if (bx != by) d_strip(Kf, Wf, cb, gc0, SB, Ast, Wst, tid);
        float (*PB)[129] = (bx == by) ? SA : SB;
        __syncthreads();
        float acc[4][4];
#pragma unroll
        for (int i = 0; i < 4; ++i)
#pragma unroll
            for (int j = 0; j < 4; ++j) acc[i][j] = 0.0f;
        for (int t = 0; t < 128; ++t) {
            float a[4], b[4];
#pragma unroll
            for (int i = 0; i < 4; ++i) a[i] = SA[ty * 4 + i][t];
#pragma unroll
            for (int j = 0; j < 4; ++j) b[j] = PB[tx * 4 + j][t];
#pragma unroll
            for (int i = 0; i < 4; ++i)
#pragma unroll
                for (int j = 0; j < 4; ++j) acc[i][j] = fmaf(a[i], b[j], acc[i][j]);
        }
#pragma unroll
        for (int i = 0; i < 4; ++i)
#pragma unroll
            for (int j = 0; j < 4; ++j)
                Kf[(size_t)(gr0 + ty * 4 + i) * M_N + gc0 + tx * 4 + j] -= acc[i][j];
        if (by == bx) {
            for (int idx = tid; idx < 64 * 128; idx += 256)
                Lf[(size_t)(gr0 + (idx >> 7)) * M_N + cb + (idx & 127)] =
                    SA[idx >> 7][idx & 127];
        }
    }
}

// ---------------- trtri v4: v3 + nounroll on chunk streams (kill load-buffer spill) ---
__global__ __launch_bounds__(512) void kw_trtri(const float* __restrict__ Lf,
                                                float* __restrict__ Wf) {
    __shared__ float Pt[128][17];     // P_t staged for W_tt apply
    __shared__ float Wcur[128][17];   // current W_tj tile
    int j  = blockIdx.y;              // 0..6
    int ct = blockIdx.x;              // 0..7
    int c0 = j * BS + ct * 16;
    int tid = threadIdx.x;
    int rq = tid >> 2, cq = tid & 3;
    int cbase = cq * 4;

    float acc[7][4];
#pragma unroll
    for (int pi = 0; pi < 7; ++pi)
#pragma unroll
        for (int c = 0; c < 4; ++c) acc[pi][c] = 0.0f;

    for (int t = j; t < 8; ++t) {
        // ---- step A: obtain W_tj tile into Wcur ----
        if (t == j) {
            for (int idx = tid; idx < 128 * 16; idx += 512) {
                int rr = idx >> 4, cc = idx & 15;
                int gr = j * BS + rr, gc = c0 + cc;
                Wcur[rr][cc] = (gr >= gc) ? Wf[(size_t)gr * M_N + gc] : 0.0f;
            }
            __syncthreads();
        } else {
            int pt = t - j - 1;
#pragma unroll
            for (int pi = 0; pi < 7; ++pi)
                if (pi == pt) {
#pragma unroll
                    for (int c = 0; c < 4; ++c) Pt[rq][cbase + c] = acc[pi][c];
                }
            __syncthreads();
            float wv[4];
#pragma unroll
            for (int c = 0; c < 4; ++c) wv[c] = 0.0f;
            const float* wrow = Wf + (size_t)(t * BS + rq) * M_N + t * BS;
#pragma unroll 1
            for (int ch = 0; ch < 16; ++ch) {      // nounroll: keep 8-float live set
                float l8[8];
                *(float4*)&l8[0] = *(const float4*)&wrow[ch * 8];
                *(float4*)&l8[4] = *(const float4*)&wrow[ch * 8 + 4];
#pragma unroll
                for (int kk = 0; kk < 8; ++kk) {
                    int k = ch * 8 + kk;
                    float lv = (k <= rq) ? l8[kk] : 0.0f;
#pragma unroll
                    for (int c = 0; c < 4; ++c)
                        wv[c] = fmaf(lv, Pt[k][cbase + c], wv[c]);
                }
            }
#pragma unroll
            for (int c = 0; c < 4; ++c) {
                float v = -wv[c];
                Wcur[rq][cbase + c] = v;
                Wf[(size_t)(t * BS + rq) * M_N + c0 + cbase + c] = v;
            }
            __syncthreads();
        }
        // ---- step B: P_i += L_it * W_tj for all i > t (barrier-free) ----
        if (t < 7) {
#pragma unroll
            for (int pi = 0; pi < 7; ++pi) {
                int i = j + 1 + pi;
                if (i <= 7 && i > t) {
                    const float* lrow = Lf + (size_t)(i * BS + rq) * M_N + t * BS;
#pragma unroll 1
                    for (int ch = 0; ch < 16; ++ch) {   // nounroll
                        float l8[8];
                        *(float4*)&l8[0] = *(const float4*)&lrow[ch * 8];
                        *(float4*)&l8[4] = *(const float4*)&lrow[ch * 8 + 4];
#pragma unroll
                        for (int kk = 0; kk < 8; ++kk) {
#pragma unroll
                            for (int c = 0; c < 4; ++c)
                                acc[pi][c] = fmaf(l8[kk], Wcur[ch * 8 + kk][cbase + c],
                                                  acc[pi][c]);
                        }
                    }
                }
            }
        }
    }
}

// ---------------- pack W (fp32) into MFMA B-fragment order, fp16 hi/lo ----------------
__global__ void kw_pack(const float* __restrict__ Wf, _Float16* __restrict__ Wph,
                        _Float16* __restrict__ Wpl) {
    int T = blockIdx.x * 256 + threadIdx.x;
    int lane = T & 63, fid = T >> 6;
    int jn = fid & 63, kik = fid >> 6;
    int ki = kik & 3, kc = kik >> 2;
    int j  = jn * 16 + (lane & 15);
    int kb = kc * 128 + ki * 32 + (lane >> 4) * 8;
    f16x8 h, lo;
#pragma unroll
    for (int e = 0; e < 8; ++e) {
        int k = kb + e;
        float v = (k <= j) ? Wf[(size_t)j * M_N + k] : 0.0f;
        _Float16 hh = (_Float16)v;
        h[e]  = hh;
        lo[e] = (_Float16)(v - (float)hh);
    }
    size_t off = (size_t)fid * 512 + lane * 8;
    *(f16x8*)(Wph + off) = h;
    *(f16x8*)(Wpl + off) = lo;
}

// ---------------- main fused MFMA kernel: 32 rows x 1024 cols, FULL tile in LDS -------
__global__ __launch_bounds__(512, 4) void k_mm(const float* __restrict__ x_star,
                                               const float* __restrict__ pf,
                                               const float* __restrict__ Zst,
                                               const _Float16* __restrict__ Wph,
                                               const _Float16* __restrict__ Wpl,
                                               float* __restrict__ out, int Bq) {
    __shared__ __align__(16) char kls[32 * 2048];   // [row][1024 fp16], 16B-slot swizzled
    __shared__ float red_l[32];
    int tid  = threadIdx.x;
    int slab = blockIdx.x;
    int w = tid >> 6, lane = tid & 63;
    int lrow = lane & 15, kgrp = lane >> 4;

    int scc = tid & 15, srow = tid >> 4;
    int q0 = slab * 32 + srow;
    int qa = (q0 < Bq) ? q0 : (Bq - 1);
    float xa0 = x_star[(size_t)qa * 5 + 0] * pf[0];
    float xa1 = x_star[(size_t)qa * 5 + 1] * pf[1];
    float xa2 = x_star[(size_t)qa * 5 + 2] * pf[2];
    float xa3 = x_star[(size_t)qa * 5 + 3] * pf[3];
    float xa4 = x_star[(size_t)qa * 5 + 4] * pf[4];
    float pv = pf[5];
    if (tid < 32) red_l[tid] = 0.0f;

    int swz = (srow & 15) << 4;
    for (int kc = 0; kc < 8; ++kc) {
        f16x8 h0;
#pragma unroll
        for (int bb = 0; bb < 2; ++bb) {
            int lb = kc * 128 + scc * 8 + bb * 4;
            float z0[4], z1[4], z2[4], z3[4], z4[4];
            *(float4*)z0 = *(const float4*)&Zst[lb];
            *(float4*)z1 = *(const float4*)&Zst[M_N + lb];
            *(float4*)z2 = *(const float4*)&Zst[2 * M_N + lb];
            *(float4*)z3 = *(const float4*)&Zst[3 * M_N + lb];
            *(float4*)z4 = *(const float4*)&Zst[4 * M_N + lb];
#pragma unroll
            for (int e = 0; e < 4; ++e) {
                float dx0 = xa0 - z0[e], dx1 = xa1 - z1[e], dx2 = xa2 - z2[e],
                      dx3 = xa3 - z3[e], dx4 = xa4 - z4[e];
                float d2 = dx0 * dx0 + dx1 * dx1 + dx2 * dx2 + dx3 * dx3 + dx4 * dx4;
                float dd = d2 + 1e-8f;
                float dist = sqrtf(dd);
                float sv = 2.23606798f * dist;
                h0[bb * 4 + e] = (_Float16)(pv * (1.0f + sv + 1.66666667f * dd) * __expf(-sv));
            }
        }
        int cb = kc * 256 + scc * 16;
        *(f16x8*)(&kls[srow * 2048 + (cb ^ swz)]) = h0;
    }
    __syncthreads();                             // the ONE barrier

    for (int jg = 0; jg < 4; ++jg) {
        f32x4 acc[2][2];
#pragma unroll
        for (int mi = 0; mi < 2; ++mi)
#pragma unroll
            for (int nj = 0; nj < 2; ++nj) acc[mi][nj] = (f32x4)(0.0f);

        int jng_hi = jg * 16 + 8 + ((w + 1) & 7);
        int jmax_w = jng_hi * 16 + 15;

        for (int kt = 0; kt < 32; ++kt) {
            int kmin = kt * 32;
            if (kmin > jmax_w) break;
            f16x8 A_[2];
#pragma unroll
            for (int mi = 0; mi < 2; ++mi) {
                int row = mi * 16 + lrow;
                int cb  = kt * 64 + kgrp * 16;
                A_[mi] = *(const f16x8*)(&kls[row * 2048 + (cb ^ ((row & 15) << 4))]);
            }
#pragma unroll
            for (int nj = 0; nj < 2; ++nj) {
                int jng = jg * 16 + nj * 8 + ((w + nj) & 7);
                if (kmin > jng * 16 + 15) continue;
                size_t fo = ((size_t)(kt * 64 + jng)) * 512 + lane * 8;
                f16x8 Bh = *(const f16x8*)(Wph + fo);
                f16x8 Bl = *(const f16x8*)(Wpl + fo);
#pragma unroll
                for (int mi = 0; mi < 2; ++mi) {
                    acc[mi][nj] = __builtin_amdgcn_mfma_f32_16x16x32_f16(A_[mi], Bh, acc[mi][nj], 0, 0, 0);
                    acc[mi][nj] = __builtin_amdgcn_mfma_f32_16x16x32_f16(A_[mi], Bl, acc[mi][nj], 0, 0, 0);
                }
            }
        }
#pragma unroll
        for (int mi = 0; mi < 2; ++mi) {
#pragma unroll
            for (int q = 0; q < 4; ++q) {
                float s = 0.0f;
#pragma unroll
                for (int nj = 0; nj < 2; ++nj) s = fmaf(acc[mi][nj][q], acc[mi][nj][q], s);
                s += __shfl_xor(s, 1);
                s += __shfl_xor(s, 2);
                s += __shfl_xor(s, 4);
                s += __shfl_xor(s, 8);
                if (lrow == 0) atomicAdd(&red_l[mi * 16 + kgrp * 4 + q], s);
            }
        }
    }
    __syncthreads();
    if (tid < 32) {
        int b = slab * 32 + tid;
        if (b < Bq) out[b] = sqrtf(fmaxf(pv - red_l[tid], 1e-6f));
    }
}

extern "C" void kernel_launch(void* const* d_in, const int* in_sizes, int n_in,
                              void* d_out, int out_size, void* d_ws, size_t ws_size,
                              hipStream_t stream) {
    const float* x_star  = (const float*)d_in[0];
    const float* log_ls  = (const float*)d_in[1];
    const float* log_var = (const float*)d_in[2];
    const float* Z_raw   = (const float*)d_in[3];
    float* out = (float*)d_out;
    int Bq = in_sizes[0] / 5;

    char* ws = (char*)d_ws;
    float*     Kf  = (float*)(ws + OFF_KF);
    float*     Lf  = (float*)(ws + OFF_LF);
    float*     Wf  = (float*)(ws + OFF_WF);
    _Float16*  Wph = (_Float16*)(ws + OFF_WPH);
    _Float16*  Wpl = (_Float16*)(ws + OFF_WPL);
    float*     pf  = (float*)(ws + OFF_PF);
    float*     Zst = (float*)(ws + OFF_ZT);

    k_build<<<4096, 256, 0, stream>>>(log_ls, log_var, Z_raw, Kf, pf, Zst);
    kw_diag<<<64, 512, 0, stream>>>(Kf, Wf, 0);
    for (int kb = 0; kb < NBK - 1; ++kb) {
        int nt = (NBK - 1 - kb) * 2;
        int grid = nt * (nt + 1) / 2 - 2;
        if (grid < 64) grid = 64;                // tiny-grid stall mitigation
        kw_step<<<grid, 256, 0, stream>>>(Kf, Wf, Lf, kb);
    }
    kw_trtri<<<dim3(8, 7), 512, 0, stream>>>(Lf, Wf);
    kw_pack<<<512, 256, 0, stream>>>(Wf, Wph, Wpl);

    int slabs = (Bq + 31) / 32;
    k_mm<<<slabs, 512, 0, stream>>>(x_star, pf, Zst, Wph, Wpl, out, Bq);
}